// Round 2
// baseline (530.715 us; speedup 1.0000x reference)
//
#include <hip/hip_runtime.h>

#define NN 50000
#define EE 800000
#define IND 256
#define HD 128

// ============ fc1: h = relu(x @ W1 + b1) ============
// 256 threads, 64-row x 128-col tile, each thread 8r x 4c, BK=64.
__global__ __launch_bounds__(256) void fc1_kernel(const float* __restrict__ x,
                                                  const float* __restrict__ W1,
                                                  const float* __restrict__ b1,
                                                  float* __restrict__ h) {
  __shared__ float As[64][64];    // [m][k] 16 KB
  __shared__ float Ws[64][HD];    // [k][c] 32 KB
  const int tid = threadIdx.x;
  const int row0 = blockIdx.x * 64;
  const int r0 = (tid >> 5) * 8;
  const int c0 = (tid & 31) * 4;

  float acc[8][4];
  const float4 bb = *(const float4*)&b1[c0];
#pragma unroll
  for (int r = 0; r < 8; ++r) {
    acc[r][0] = bb.x; acc[r][1] = bb.y; acc[r][2] = bb.z; acc[r][3] = bb.w;
  }

  for (int kt = 0; kt < 4; ++kt) {
    const int k0 = kt * 64;
    // stage A: 64 rows x 64 k = 1024 float4, 4 per thread
#pragma unroll
    for (int i = 0; i < 4; ++i) {
      const int f = tid + i * 256;
      const int row = f >> 4;
      const int kq = f & 15;
      int rg = row0 + row; if (rg >= NN) rg = NN - 1;   // clamp: avoid OOB fault
      *(float4*)&As[row][kq * 4] = *(const float4*)&x[(size_t)rg * IND + k0 + kq * 4];
    }
    // stage W: 64 k x 128 c = 2048 float4, 8 per thread
#pragma unroll
    for (int i = 0; i < 8; ++i) {
      const int f = tid + i * 256;
      const int k = f >> 5;
      const int cq = f & 31;
      *(float4*)&Ws[k][cq * 4] = *(const float4*)&W1[(size_t)(k0 + k) * HD + cq * 4];
    }
    __syncthreads();
#pragma unroll
    for (int kq = 0; kq < 16; ++kq) {
      float4 a[8];
#pragma unroll
      for (int r = 0; r < 8; ++r) a[r] = *(const float4*)&As[r0 + r][kq * 4];
#pragma unroll
      for (int kk = 0; kk < 4; ++kk) {
        const float4 wv = *(const float4*)&Ws[kq * 4 + kk][c0];
#pragma unroll
        for (int r = 0; r < 8; ++r) {
          const float av = ((const float*)&a[r])[kk];
          acc[r][0] = fmaf(av, wv.x, acc[r][0]);
          acc[r][1] = fmaf(av, wv.y, acc[r][1]);
          acc[r][2] = fmaf(av, wv.z, acc[r][2]);
          acc[r][3] = fmaf(av, wv.w, acc[r][3]);
        }
      }
    }
    __syncthreads();
  }
#pragma unroll
  for (int r = 0; r < 8; ++r) {
    const int rg = row0 + r0 + r;
    if (rg < NN) {
      float4 o;
      o.x = fmaxf(acc[r][0], 0.f); o.y = fmaxf(acc[r][1], 0.f);
      o.z = fmaxf(acc[r][2], 0.f); o.w = fmaxf(acc[r][3], 0.f);
      *(float4*)&h[(size_t)rg * HD + c0] = o;
    }
  }
}

// ============ CSR build ============
__global__ void hist_kernel(const int* __restrict__ rows, int* __restrict__ counts) {
  int e = blockIdx.x * 256 + threadIdx.x;
  if (e < EE) atomicAdd(&counts[rows[e]], 1);
}

__device__ inline int wave_incl_scan(int v, int lane) {
#pragma unroll
  for (int off = 1; off < 64; off <<= 1) {
    int n = __shfl_up(v, off);
    if (lane >= off) v += n;
  }
  return v;
}

// single-block scan, 4 elems/thread (13 iterations over 50000)
__global__ __launch_bounds__(1024) void scan_kernel(const int* __restrict__ counts,
                                                    int* __restrict__ row_ptr,
                                                    int* __restrict__ cursor) {
  __shared__ int wsum[16];
  __shared__ int carry_s;
  const int t = threadIdx.x;
  const int lane = t & 63;
  const int wid = t >> 6;
  if (t == 0) { carry_s = 0; row_ptr[0] = 0; }
  __syncthreads();
  for (int base = 0; base < NN; base += 4096) {
    const int i0 = base + t * 4;
    int v0 = (i0 + 0 < NN) ? counts[i0 + 0] : 0;
    int v1 = (i0 + 1 < NN) ? counts[i0 + 1] : 0;
    int v2 = (i0 + 2 < NN) ? counts[i0 + 2] : 0;
    int v3 = (i0 + 3 < NN) ? counts[i0 + 3] : 0;
    const int s0 = v0, s1 = s0 + v1, s2 = s1 + v2, s3 = s2 + v3;
    int sc = wave_incl_scan(s3, lane);
    if (lane == 63) wsum[wid] = sc;
    __syncthreads();
    if (wid == 0) {
      int ws = (lane < 16) ? wsum[lane] : 0;
      int wsc = wave_incl_scan(ws, lane);
      if (lane < 16) wsum[lane] = wsc - ws;  // exclusive wave offsets
    }
    __syncthreads();
    const int excl = carry_s + wsum[wid] + (sc - s3);  // exclusive prefix for i0
    __syncthreads();
    if (i0 + 0 < NN) { cursor[i0 + 0] = excl;      row_ptr[i0 + 1] = excl + s0; }
    if (i0 + 1 < NN) { cursor[i0 + 1] = excl + s0; row_ptr[i0 + 2] = excl + s1; }
    if (i0 + 2 < NN) { cursor[i0 + 2] = excl + s1; row_ptr[i0 + 3] = excl + s2; }
    if (i0 + 3 < NN) { cursor[i0 + 3] = excl + s2; row_ptr[i0 + 4] = excl + s3; }
    if (t == 1023) carry_s = excl + s3;
    __syncthreads();
  }
}

__global__ void permute_kernel(const int* __restrict__ rows, const int* __restrict__ cols,
                               const float* __restrict__ vals, int* __restrict__ cursor,
                               float* __restrict__ vals_s, int* __restrict__ cols_s) {
  int e = blockIdx.x * 256 + threadIdx.x;
  if (e < EE) {
    int r = rows[e];
    int pos = atomicAdd(&cursor[r], 1);
    vals_s[pos] = vals[e];
    cols_s[pos] = cols[e];
  }
}

// ============ SpMM: one wave per node, float2 per lane ============
__global__ __launch_bounds__(256) void spmm_kernel(const float* __restrict__ h,
                                                   const float* __restrict__ vals_s,
                                                   const int* __restrict__ cols_s,
                                                   const int* __restrict__ row_ptr,
                                                   float* __restrict__ agg) {
  const int wid = threadIdx.x >> 6;
  const int lane = threadIdx.x & 63;
  const int node = blockIdx.x * 4 + wid;
  if (node >= NN) return;
  const int s = row_ptr[node];
  const int e = row_ptr[node + 1];
  const float2* __restrict__ h2 = (const float2*)h;
  float ax = 0.f, ay = 0.f;
  int t = s;
  for (; t + 1 < e; t += 2) {
    const int c0 = cols_s[t];
    const int c1 = cols_s[t + 1];
    const float v0 = vals_s[t];
    const float v1 = vals_s[t + 1];
    const float2 g0 = h2[(size_t)c0 * 64 + lane];
    const float2 g1 = h2[(size_t)c1 * 64 + lane];
    ax = fmaf(v0, g0.x, ax); ay = fmaf(v0, g0.y, ay);
    ax = fmaf(v1, g1.x, ax); ay = fmaf(v1, g1.y, ay);
  }
  if (t < e) {
    const int c = cols_s[t];
    const float v = vals_s[t];
    const float2 g = h2[(size_t)c * 64 + lane];
    ax = fmaf(v, g.x, ax); ay = fmaf(v, g.y, ay);
  }
  float2 o; o.x = ax; o.y = ay;
  ((float2*)agg)[(size_t)node * 64 + lane] = o;
}

// ============ fused fc2 -> fc2 -> softmax ============
// 256 threads, 64-row tile, full 128-col width; each thread 8r x 4c.
// tile[][] holds agg rows, then is overwritten with h2. W2 k-tiles staged in Ws.
__global__ __launch_bounds__(256) void fc2x2_softmax_kernel(const float* __restrict__ agg,
                                                            const float* __restrict__ W2,
                                                            const float* __restrict__ b2,
                                                            float* __restrict__ out) {
  __shared__ float tile[64][HD];  // 32 KB: A, then h2
  __shared__ float Ws[64][HD];    // 32 KB: W2 k-tile
  const int tid = threadIdx.x;
  const int row0 = blockIdx.x * 64;
  const int r0 = (tid >> 5) * 8;
  const int c0 = (tid & 31) * 4;
  const int lane = tid & 63;

  const float4 bb = *(const float4*)&b2[c0];
  float acc[8][4];

  // ---- stage A tile (rows may read past agg but stay inside d_ws) ----
#pragma unroll
  for (int i = 0; i < 8; ++i) {
    const int f = tid + i * 256;
    const int row = f >> 5;
    const int cq = f & 31;
    *(float4*)&tile[row][cq * 4] = *(const float4*)&agg[(size_t)(row0 + row) * HD + cq * 4];
  }

#pragma unroll
  for (int stage = 0; stage < 2; ++stage) {
#pragma unroll
    for (int r = 0; r < 8; ++r) {
      acc[r][0] = bb.x; acc[r][1] = bb.y; acc[r][2] = bb.z; acc[r][3] = bb.w;
    }
#pragma unroll
    for (int kt = 0; kt < 2; ++kt) {
      const int k0 = kt * 64;
      // stage W2 k-tile
#pragma unroll
      for (int i = 0; i < 8; ++i) {
        const int f = tid + i * 256;
        const int k = f >> 5;
        const int cq = f & 31;
        *(float4*)&Ws[k][cq * 4] = *(const float4*)&W2[(size_t)(k0 + k) * HD + cq * 4];
      }
      __syncthreads();
#pragma unroll
      for (int kq = 0; kq < 16; ++kq) {
        float4 a[8];
#pragma unroll
        for (int r = 0; r < 8; ++r) a[r] = *(const float4*)&tile[r0 + r][k0 + kq * 4];
#pragma unroll
        for (int kk = 0; kk < 4; ++kk) {
          const float4 wv = *(const float4*)&Ws[kq * 4 + kk][c0];
#pragma unroll
          for (int r = 0; r < 8; ++r) {
            const float av = ((const float*)&a[r])[kk];
            acc[r][0] = fmaf(av, wv.x, acc[r][0]);
            acc[r][1] = fmaf(av, wv.y, acc[r][1]);
            acc[r][2] = fmaf(av, wv.z, acc[r][2]);
            acc[r][3] = fmaf(av, wv.w, acc[r][3]);
          }
        }
      }
      __syncthreads();
    }
    if (stage == 0) {
      // write h2 into tile for stage 2
#pragma unroll
      for (int r = 0; r < 8; ++r)
        *(float4*)&tile[r0 + r][c0] = *(float4*)&acc[r][0];
      __syncthreads();
    }
  }

  // ---- softmax per row: reduce across the 32 threads sharing a row ----
#pragma unroll
  for (int r = 0; r < 8; ++r) {
    float m = fmaxf(fmaxf(acc[r][0], acc[r][1]), fmaxf(acc[r][2], acc[r][3]));
#pragma unroll
    for (int off = 1; off < 32; off <<= 1) m = fmaxf(m, __shfl_xor(m, off));
    float p0 = __expf(acc[r][0] - m);
    float p1 = __expf(acc[r][1] - m);
    float p2 = __expf(acc[r][2] - m);
    float p3 = __expf(acc[r][3] - m);
    float ss = (p0 + p1) + (p2 + p3);
#pragma unroll
    for (int off = 1; off < 32; off <<= 1) ss += __shfl_xor(ss, off);
    const float inv = 1.f / ss;
    const int rg = row0 + r0 + r;
    if (rg < NN) {
      float4 o; o.x = p0 * inv; o.y = p1 * inv; o.z = p2 * inv; o.w = p3 * inv;
      *(float4*)&out[(size_t)rg * HD + c0] = o;
    }
  }
  (void)lane;
}

// ============ launch ============
extern "C" void kernel_launch(void* const* d_in, const int* in_sizes, int n_in,
                              void* d_out, int out_size, void* d_ws, size_t ws_size,
                              hipStream_t stream) {
  (void)in_sizes; (void)n_in; (void)out_size; (void)ws_size;
  const float* x   = (const float*)d_in[0];
  const float* W1  = (const float*)d_in[1];
  const float* b1  = (const float*)d_in[2];
  const float* W2  = (const float*)d_in[3];
  const float* b2  = (const float*)d_in[4];
  const float* adj_vals = (const float*)d_in[5];
  const int* adj_rows   = (const int*)d_in[6];
  const int* adj_cols   = (const int*)d_in[7];
  float* out = (float*)d_out;

  float* h      = (float*)d_ws;                    // 6,400,000 floats
  float* agg    = h + (size_t)NN * HD;             // 6,400,000 floats
  int* row_ptr  = (int*)(agg + (size_t)NN * HD);   // 50001 (pad to 50016)
  int* cursor   = row_ptr + 50016;
  int* counts   = cursor + 50016;
  float* vals_s = (float*)(counts + 50016);        // 800,000 floats
  int* cols_s   = (int*)(vals_s + EE);             // 800,000 ints

  hipMemsetAsync(counts, 0, NN * sizeof(int), stream);

  fc1_kernel<<<(NN + 63) / 64, 256, 0, stream>>>(x, W1, b1, h);
  hist_kernel<<<(EE + 255) / 256, 256, 0, stream>>>(adj_rows, counts);
  scan_kernel<<<1, 1024, 0, stream>>>(counts, row_ptr, cursor);
  permute_kernel<<<(EE + 255) / 256, 256, 0, stream>>>(adj_rows, adj_cols, adj_vals,
                                                       cursor, vals_s, cols_s);
  spmm_kernel<<<(NN + 3) / 4, 256, 0, stream>>>(h, vals_s, cols_s, row_ptr, agg);
  fc2x2_softmax_kernel<<<(NN + 63) / 64, 256, 0, stream>>>(agg, W2, b2, out);
}

// Round 3
// 410.133 us; speedup vs baseline: 1.2940x; 1.2940x over previous
//
#include <hip/hip_runtime.h>

#define NN 50000
#define EE 800000
#define IND 256
#define HD 128

// ============ fc1: h = relu(x @ W1 + b1) ============
// 256 threads, 64-row x 128-col tile, each thread 8r x 4c, BK=64.
// NOTE: kq loop deliberately unroll-2 only — full unroll spilled (256 VGPR,
// 370MB scratch traffic, 2.3x slowdown) in round 2.
__global__ __launch_bounds__(256) void fc1_kernel(const float* __restrict__ x,
                                                  const float* __restrict__ W1,
                                                  const float* __restrict__ b1,
                                                  float* __restrict__ h) {
  __shared__ float As[64][64];    // [m][k] 16 KB
  __shared__ float Ws[64][HD];    // [k][c] 32 KB
  const int tid = threadIdx.x;
  const int row0 = blockIdx.x * 64;
  const int r0 = (tid >> 5) * 8;
  const int c0 = (tid & 31) * 4;

  float acc[8][4];
  const float4 bb = *(const float4*)&b1[c0];
#pragma unroll
  for (int r = 0; r < 8; ++r) {
    acc[r][0] = bb.x; acc[r][1] = bb.y; acc[r][2] = bb.z; acc[r][3] = bb.w;
  }

#pragma unroll 1
  for (int kt = 0; kt < 4; ++kt) {
    const int k0 = kt * 64;
    // stage A: 64 rows x 64 k = 1024 float4, 4 per thread
#pragma unroll
    for (int i = 0; i < 4; ++i) {
      const int f = tid + i * 256;
      const int row = f >> 4;
      const int kq = f & 15;
      int rg = row0 + row; if (rg >= NN) rg = NN - 1;   // clamp: avoid OOB fault
      *(float4*)&As[row][kq * 4] = *(const float4*)&x[(size_t)rg * IND + k0 + kq * 4];
    }
    // stage W: 64 k x 128 c = 2048 float4, 8 per thread
#pragma unroll
    for (int i = 0; i < 8; ++i) {
      const int f = tid + i * 256;
      const int k = f >> 5;
      const int cq = f & 31;
      *(float4*)&Ws[k][cq * 4] = *(const float4*)&W1[(size_t)(k0 + k) * HD + cq * 4];
    }
    __syncthreads();
#pragma unroll 2
    for (int kq = 0; kq < 16; ++kq) {
      float4 a[8];
#pragma unroll
      for (int r = 0; r < 8; ++r) a[r] = *(const float4*)&As[r0 + r][kq * 4];
#pragma unroll
      for (int kk = 0; kk < 4; ++kk) {
        const float4 wv = *(const float4*)&Ws[kq * 4 + kk][c0];
#pragma unroll
        for (int r = 0; r < 8; ++r) {
          const float av = ((const float*)&a[r])[kk];
          acc[r][0] = fmaf(av, wv.x, acc[r][0]);
          acc[r][1] = fmaf(av, wv.y, acc[r][1]);
          acc[r][2] = fmaf(av, wv.z, acc[r][2]);
          acc[r][3] = fmaf(av, wv.w, acc[r][3]);
        }
      }
    }
    __syncthreads();
  }
#pragma unroll
  for (int r = 0; r < 8; ++r) {
    const int rg = row0 + r0 + r;
    if (rg < NN) {
      float4 o;
      o.x = fmaxf(acc[r][0], 0.f); o.y = fmaxf(acc[r][1], 0.f);
      o.z = fmaxf(acc[r][2], 0.f); o.w = fmaxf(acc[r][3], 0.f);
      *(float4*)&h[(size_t)rg * HD + c0] = o;
    }
  }
}

// ============ CSR build ============
__global__ void hist_kernel(const int* __restrict__ rows, int* __restrict__ counts) {
  int e = blockIdx.x * 256 + threadIdx.x;
  if (e < EE) atomicAdd(&counts[rows[e]], 1);
}

__device__ inline int wave_incl_scan(int v, int lane) {
#pragma unroll
  for (int off = 1; off < 64; off <<= 1) {
    int n = __shfl_up(v, off);
    if (lane >= off) v += n;
  }
  return v;
}

// single-block scan, 4 elems/thread (13 iterations over 50000)
__global__ __launch_bounds__(1024) void scan_kernel(const int* __restrict__ counts,
                                                    int* __restrict__ row_ptr,
                                                    int* __restrict__ cursor) {
  __shared__ int wsum[16];
  __shared__ int carry_s;
  const int t = threadIdx.x;
  const int lane = t & 63;
  const int wid = t >> 6;
  if (t == 0) { carry_s = 0; row_ptr[0] = 0; }
  __syncthreads();
  for (int base = 0; base < NN; base += 4096) {
    const int i0 = base + t * 4;
    int v0 = (i0 + 0 < NN) ? counts[i0 + 0] : 0;
    int v1 = (i0 + 1 < NN) ? counts[i0 + 1] : 0;
    int v2 = (i0 + 2 < NN) ? counts[i0 + 2] : 0;
    int v3 = (i0 + 3 < NN) ? counts[i0 + 3] : 0;
    const int s0 = v0, s1 = s0 + v1, s2 = s1 + v2, s3 = s2 + v3;
    int sc = wave_incl_scan(s3, lane);
    if (lane == 63) wsum[wid] = sc;
    __syncthreads();
    if (wid == 0) {
      int ws = (lane < 16) ? wsum[lane] : 0;
      int wsc = wave_incl_scan(ws, lane);
      if (lane < 16) wsum[lane] = wsc - ws;  // exclusive wave offsets
    }
    __syncthreads();
    const int excl = carry_s + wsum[wid] + (sc - s3);  // exclusive prefix for i0
    __syncthreads();
    if (i0 + 0 < NN) { cursor[i0 + 0] = excl;      row_ptr[i0 + 1] = excl + s0; }
    if (i0 + 1 < NN) { cursor[i0 + 1] = excl + s0; row_ptr[i0 + 2] = excl + s1; }
    if (i0 + 2 < NN) { cursor[i0 + 2] = excl + s1; row_ptr[i0 + 3] = excl + s2; }
    if (i0 + 3 < NN) { cursor[i0 + 3] = excl + s2; row_ptr[i0 + 4] = excl + s3; }
    if (t == 1023) carry_s = excl + s3;
    __syncthreads();
  }
}

__global__ void permute_kernel(const int* __restrict__ rows, const int* __restrict__ cols,
                               const float* __restrict__ vals, int* __restrict__ cursor,
                               float* __restrict__ vals_s, int* __restrict__ cols_s) {
  int e = blockIdx.x * 256 + threadIdx.x;
  if (e < EE) {
    int r = rows[e];
    int pos = atomicAdd(&cursor[r], 1);
    vals_s[pos] = vals[e];
    cols_s[pos] = cols[e];
  }
}

// ============ SpMM: one wave per node, float2 per lane, 4 gathers in flight ============
__global__ __launch_bounds__(256) void spmm_kernel(const float* __restrict__ h,
                                                   const float* __restrict__ vals_s,
                                                   const int* __restrict__ cols_s,
                                                   const int* __restrict__ row_ptr,
                                                   float* __restrict__ agg) {
  const int wid = threadIdx.x >> 6;
  const int lane = threadIdx.x & 63;
  const int node = blockIdx.x * 4 + wid;
  if (node >= NN) return;
  const int s = row_ptr[node];
  const int e = row_ptr[node + 1];
  const float2* __restrict__ h2 = (const float2*)h;
  float ax = 0.f, ay = 0.f;
  int t = s;
  for (; t + 3 < e; t += 4) {
    const int c0 = cols_s[t];
    const int c1 = cols_s[t + 1];
    const int c2 = cols_s[t + 2];
    const int c3 = cols_s[t + 3];
    const float v0 = vals_s[t];
    const float v1 = vals_s[t + 1];
    const float v2 = vals_s[t + 2];
    const float v3 = vals_s[t + 3];
    const float2 g0 = h2[(size_t)c0 * 64 + lane];
    const float2 g1 = h2[(size_t)c1 * 64 + lane];
    const float2 g2 = h2[(size_t)c2 * 64 + lane];
    const float2 g3 = h2[(size_t)c3 * 64 + lane];
    ax = fmaf(v0, g0.x, ax); ay = fmaf(v0, g0.y, ay);
    ax = fmaf(v1, g1.x, ax); ay = fmaf(v1, g1.y, ay);
    ax = fmaf(v2, g2.x, ax); ay = fmaf(v2, g2.y, ay);
    ax = fmaf(v3, g3.x, ax); ay = fmaf(v3, g3.y, ay);
  }
  for (; t < e; ++t) {
    const int c = cols_s[t];
    const float v = vals_s[t];
    const float2 g = h2[(size_t)c * 64 + lane];
    ax = fmaf(v, g.x, ax); ay = fmaf(v, g.y, ay);
  }
  float2 o; o.x = ax; o.y = ay;
  ((float2*)agg)[(size_t)node * 64 + lane] = o;
}

// ============ fused fc2 -> fc2 -> softmax ============
// 256 threads, 64-row tile, full 128-col width; each thread 8r x 4c.
// tile[][] holds agg rows, then is overwritten with h2. W2 k-tiles staged in Ws.
__global__ __launch_bounds__(256) void fc2x2_softmax_kernel(const float* __restrict__ agg,
                                                            const float* __restrict__ W2,
                                                            const float* __restrict__ b2,
                                                            float* __restrict__ out) {
  __shared__ float tile[64][HD];  // 32 KB: A, then h2
  __shared__ float Ws[64][HD];    // 32 KB: W2 k-tile
  const int tid = threadIdx.x;
  const int row0 = blockIdx.x * 64;
  const int r0 = (tid >> 5) * 8;
  const int c0 = (tid & 31) * 4;

  const float4 bb = *(const float4*)&b2[c0];
  float acc[8][4];

  // ---- stage A tile (tail rows read past agg but stay inside d_ws) ----
#pragma unroll
  for (int i = 0; i < 8; ++i) {
    const int f = tid + i * 256;
    const int row = f >> 5;
    const int cq = f & 31;
    *(float4*)&tile[row][cq * 4] = *(const float4*)&agg[(size_t)(row0 + row) * HD + cq * 4];
  }

#pragma unroll 1
  for (int stage = 0; stage < 2; ++stage) {
#pragma unroll
    for (int r = 0; r < 8; ++r) {
      acc[r][0] = bb.x; acc[r][1] = bb.y; acc[r][2] = bb.z; acc[r][3] = bb.w;
    }
#pragma unroll 1
    for (int kt = 0; kt < 2; ++kt) {
      const int k0 = kt * 64;
      // stage W2 k-tile
#pragma unroll
      for (int i = 0; i < 8; ++i) {
        const int f = tid + i * 256;
        const int k = f >> 5;
        const int cq = f & 31;
        *(float4*)&Ws[k][cq * 4] = *(const float4*)&W2[(size_t)(k0 + k) * HD + cq * 4];
      }
      __syncthreads();
#pragma unroll 2
      for (int kq = 0; kq < 16; ++kq) {
        float4 a[8];
#pragma unroll
        for (int r = 0; r < 8; ++r) a[r] = *(const float4*)&tile[r0 + r][k0 + kq * 4];
#pragma unroll
        for (int kk = 0; kk < 4; ++kk) {
          const float4 wv = *(const float4*)&Ws[kq * 4 + kk][c0];
#pragma unroll
          for (int r = 0; r < 8; ++r) {
            const float av = ((const float*)&a[r])[kk];
            acc[r][0] = fmaf(av, wv.x, acc[r][0]);
            acc[r][1] = fmaf(av, wv.y, acc[r][1]);
            acc[r][2] = fmaf(av, wv.z, acc[r][2]);
            acc[r][3] = fmaf(av, wv.w, acc[r][3]);
          }
        }
      }
      __syncthreads();
    }
    if (stage == 0) {
      // write h2 into tile for stage 2
#pragma unroll
      for (int r = 0; r < 8; ++r)
        *(float4*)&tile[r0 + r][c0] = *(float4*)&acc[r][0];
      __syncthreads();
    }
  }

  // ---- softmax per row: reduce across the 32 threads sharing a row ----
#pragma unroll 1
  for (int r = 0; r < 8; ++r) {
    float m = fmaxf(fmaxf(acc[r][0], acc[r][1]), fmaxf(acc[r][2], acc[r][3]));
#pragma unroll
    for (int off = 1; off < 32; off <<= 1) m = fmaxf(m, __shfl_xor(m, off));
    float p0 = __expf(acc[r][0] - m);
    float p1 = __expf(acc[r][1] - m);
    float p2 = __expf(acc[r][2] - m);
    float p3 = __expf(acc[r][3] - m);
    float ss = (p0 + p1) + (p2 + p3);
#pragma unroll
    for (int off = 1; off < 32; off <<= 1) ss += __shfl_xor(ss, off);
    const float inv = 1.f / ss;
    const int rg = row0 + r0 + r;
    if (rg < NN) {
      float4 o; o.x = p0 * inv; o.y = p1 * inv; o.z = p2 * inv; o.w = p3 * inv;
      *(float4*)&out[(size_t)rg * HD + c0] = o;
    }
  }
}

// ============ launch ============
extern "C" void kernel_launch(void* const* d_in, const int* in_sizes, int n_in,
                              void* d_out, int out_size, void* d_ws, size_t ws_size,
                              hipStream_t stream) {
  (void)in_sizes; (void)n_in; (void)out_size; (void)ws_size;
  const float* x   = (const float*)d_in[0];
  const float* W1  = (const float*)d_in[1];
  const float* b1  = (const float*)d_in[2];
  const float* W2  = (const float*)d_in[3];
  const float* b2  = (const float*)d_in[4];
  const float* adj_vals = (const float*)d_in[5];
  const int* adj_rows   = (const int*)d_in[6];
  const int* adj_cols   = (const int*)d_in[7];
  float* out = (float*)d_out;

  float* h      = (float*)d_ws;                    // 6,400,000 floats
  float* agg    = h + (size_t)NN * HD;             // 6,400,000 floats
  int* row_ptr  = (int*)(agg + (size_t)NN * HD);   // 50001 (pad to 50016)
  int* cursor   = row_ptr + 50016;
  int* counts   = cursor + 50016;
  float* vals_s = (float*)(counts + 50016);        // 800,000 floats
  int* cols_s   = (int*)(vals_s + EE);             // 800,000 ints

  hipMemsetAsync(counts, 0, NN * sizeof(int), stream);

  fc1_kernel<<<(NN + 63) / 64, 256, 0, stream>>>(x, W1, b1, h);
  hist_kernel<<<(EE + 255) / 256, 256, 0, stream>>>(adj_rows, counts);
  scan_kernel<<<1, 1024, 0, stream>>>(counts, row_ptr, cursor);
  permute_kernel<<<(EE + 255) / 256, 256, 0, stream>>>(adj_rows, adj_cols, adj_vals,
                                                       cursor, vals_s, cols_s);
  spmm_kernel<<<(NN + 3) / 4, 256, 0, stream>>>(h, vals_s, cols_s, row_ptr, agg);
  fc2x2_softmax_kernel<<<(NN + 63) / 64, 256, 0, stream>>>(agg, W2, b2, out);
}

// Round 4
// 381.224 us; speedup vs baseline: 1.3921x; 1.0758x over previous
//
#include <hip/hip_runtime.h>
#include <hip/hip_fp16.h>

#define NN 50000
#define EE 800000
#define IND 256
#define HD 128

// ============ W2sq = W2@W2, b2eff = b2@W2 + b2 (tiny, once per launch) ============
__global__ __launch_bounds__(128) void w2sq_kernel(const float* __restrict__ W2,
                                                   const float* __restrict__ b2,
                                                   float* __restrict__ W2sq,
                                                   float* __restrict__ b2eff) {
  const int r = blockIdx.x;   // 0..127
  const int c = threadIdx.x;  // 0..127
  float acc = 0.f;
#pragma unroll 8
  for (int k = 0; k < HD; ++k)
    acc = fmaf(W2[r * HD + k], W2[k * HD + c], acc);
  W2sq[r * HD + c] = acc;
  if (r == 0) {
    float be = b2[c];
#pragma unroll 8
    for (int k = 0; k < HD; ++k)
      be = fmaf(b2[k], W2[k * HD + c], be);
    b2eff[c] = be;
  }
}

// ============ fc1: h = relu(x @ W1 + b1), h stored fp16 ============
// 256 thr, 64x128 tile, thread 8rx4c, BK=64, reg-dbuf staging (T14).
__global__ __launch_bounds__(256) void fc1_kernel(const float* __restrict__ x,
                                                  const float* __restrict__ W1,
                                                  const float* __restrict__ b1,
                                                  __half* __restrict__ h) {
  __shared__ float As[64 * 64];    // 16 KB
  __shared__ float Ws[64 * HD];    // 32 KB
  const int tid = threadIdx.x;
  const int row0 = blockIdx.x * 64;
  const int r0 = (tid >> 5) * 8;
  const int c0 = (tid & 31) * 4;

  float acc[8][4];
  const float4 bb = *(const float4*)&b1[c0];
#pragma unroll
  for (int r = 0; r < 8; ++r) {
    acc[r][0] = bb.x; acc[r][1] = bb.y; acc[r][2] = bb.z; acc[r][3] = bb.w;
  }

  float4 areg[4], wreg[8];
  // prologue: kt=0 tiles -> regs
#pragma unroll
  for (int i = 0; i < 4; ++i) {
    const int f = tid + i * 256, row = f >> 4, kq = f & 15;
    const int rg = min(row0 + row, NN - 1);
    areg[i] = *(const float4*)&x[(size_t)rg * IND + kq * 4];
  }
#pragma unroll
  for (int i = 0; i < 8; ++i) {
    const int f = tid + i * 256, k = f >> 5, cq = f & 31;
    wreg[i] = *(const float4*)&W1[(size_t)k * HD + cq * 4];
  }

#pragma unroll 1
  for (int kt = 0; kt < 4; ++kt) {
    __syncthreads();               // prior tile's readers done
#pragma unroll
    for (int i = 0; i < 4; ++i) {
      const int f = tid + i * 256, row = f >> 4, kq = f & 15;
      *(float4*)&As[row * 64 + kq * 4] = areg[i];
    }
#pragma unroll
    for (int i = 0; i < 8; ++i) {
      const int f = tid + i * 256, k = f >> 5, cq = f & 31;
      *(float4*)&Ws[k * HD + cq * 4] = wreg[i];
    }
    __syncthreads();               // tile visible
    if (kt < 3) {                  // issue next-tile loads; hide under compute
      const int k0n = (kt + 1) * 64;
#pragma unroll
      for (int i = 0; i < 4; ++i) {
        const int f = tid + i * 256, row = f >> 4, kq = f & 15;
        const int rg = min(row0 + row, NN - 1);
        areg[i] = *(const float4*)&x[(size_t)rg * IND + k0n + kq * 4];
      }
#pragma unroll
      for (int i = 0; i < 8; ++i) {
        const int f = tid + i * 256, k = f >> 5, cq = f & 31;
        wreg[i] = *(const float4*)&W1[(size_t)(k0n + k) * HD + cq * 4];
      }
    }
#pragma unroll 2
    for (int kq = 0; kq < 16; ++kq) {
      float4 a[8];
#pragma unroll
      for (int r = 0; r < 8; ++r) a[r] = *(const float4*)&As[(r0 + r) * 64 + kq * 4];
#pragma unroll
      for (int kk = 0; kk < 4; ++kk) {
        const float4 wv = *(const float4*)&Ws[(kq * 4 + kk) * HD + c0];
#pragma unroll
        for (int r = 0; r < 8; ++r) {
          const float av = ((const float*)&a[r])[kk];
          acc[r][0] = fmaf(av, wv.x, acc[r][0]);
          acc[r][1] = fmaf(av, wv.y, acc[r][1]);
          acc[r][2] = fmaf(av, wv.z, acc[r][2]);
          acc[r][3] = fmaf(av, wv.w, acc[r][3]);
        }
      }
    }
  }
  // epilogue: relu -> fp16 pack -> 8B store
#pragma unroll
  for (int r = 0; r < 8; ++r) {
    const int rg = row0 + r0 + r;
    if (rg < NN) {
      const float o0 = fmaxf(acc[r][0], 0.f), o1 = fmaxf(acc[r][1], 0.f);
      const float o2 = fmaxf(acc[r][2], 0.f), o3 = fmaxf(acc[r][3], 0.f);
      uint2 p;
      p.x = (uint)__half_as_ushort(__float2half(o0)) |
            ((uint)__half_as_ushort(__float2half(o1)) << 16);
      p.y = (uint)__half_as_ushort(__float2half(o2)) |
            ((uint)__half_as_ushort(__float2half(o3)) << 16);
      *(uint2*)&h[(size_t)rg * HD + c0] = p;
    }
  }
}

// ============ CSR build ============
__global__ void hist_kernel(const int* __restrict__ rows, int* __restrict__ counts) {
  int e = blockIdx.x * 256 + threadIdx.x;
  if (e < EE) atomicAdd(&counts[rows[e]], 1);
}

__device__ inline int wave_incl_scan(int v, int lane) {
#pragma unroll
  for (int off = 1; off < 64; off <<= 1) {
    int n = __shfl_up(v, off);
    if (lane >= off) v += n;
  }
  return v;
}

__global__ __launch_bounds__(1024) void scan_kernel(const int* __restrict__ counts,
                                                    int* __restrict__ row_ptr,
                                                    int* __restrict__ cursor) {
  __shared__ int wsum[16];
  __shared__ int carry_s;
  const int t = threadIdx.x;
  const int lane = t & 63;
  const int wid = t >> 6;
  if (t == 0) { carry_s = 0; row_ptr[0] = 0; }
  __syncthreads();
  for (int base = 0; base < NN; base += 4096) {
    const int i0 = base + t * 4;
    int v0 = (i0 + 0 < NN) ? counts[i0 + 0] : 0;
    int v1 = (i0 + 1 < NN) ? counts[i0 + 1] : 0;
    int v2 = (i0 + 2 < NN) ? counts[i0 + 2] : 0;
    int v3 = (i0 + 3 < NN) ? counts[i0 + 3] : 0;
    const int s0 = v0, s1 = s0 + v1, s2 = s1 + v2, s3 = s2 + v3;
    int sc = wave_incl_scan(s3, lane);
    if (lane == 63) wsum[wid] = sc;
    __syncthreads();
    if (wid == 0) {
      int ws = (lane < 16) ? wsum[lane] : 0;
      int wsc = wave_incl_scan(ws, lane);
      if (lane < 16) wsum[lane] = wsc - ws;
    }
    __syncthreads();
    const int excl = carry_s + wsum[wid] + (sc - s3);
    __syncthreads();
    if (i0 + 0 < NN) { cursor[i0 + 0] = excl;      row_ptr[i0 + 1] = excl + s0; }
    if (i0 + 1 < NN) { cursor[i0 + 1] = excl + s0; row_ptr[i0 + 2] = excl + s1; }
    if (i0 + 2 < NN) { cursor[i0 + 2] = excl + s1; row_ptr[i0 + 3] = excl + s2; }
    if (i0 + 3 < NN) { cursor[i0 + 3] = excl + s2; row_ptr[i0 + 4] = excl + s3; }
    if (t == 1023) carry_s = excl + s3;
    __syncthreads();
  }
}

__global__ void permute_kernel(const int* __restrict__ rows, const int* __restrict__ cols,
                               const float* __restrict__ vals, int* __restrict__ cursor,
                               uint2* __restrict__ edges_s) {
  int e = blockIdx.x * 256 + threadIdx.x;
  if (e < EE) {
    int r = rows[e];
    int pos = atomicAdd(&cursor[r], 1);
    edges_s[pos] = make_uint2(__float_as_uint(vals[e]), (unsigned)cols[e]);
  }
}

// ============ SpMM: one wave per node, fp16 h gather (4B/lane), 4-deep ============
__global__ __launch_bounds__(256) void spmm_kernel(const __half* __restrict__ h,
                                                   const uint2* __restrict__ edges,
                                                   const int* __restrict__ row_ptr,
                                                   float* __restrict__ agg) {
  const int wid = threadIdx.x >> 6;
  const int lane = threadIdx.x & 63;
  const int node = blockIdx.x * 4 + wid;
  if (node >= NN) return;
  const int s = row_ptr[node];
  const int e = row_ptr[node + 1];
  const unsigned* __restrict__ hu = (const unsigned*)h;
  float ax = 0.f, ay = 0.f;
  int t = s;
  for (; t + 3 < e; t += 4) {
    const uint2 e0 = edges[t + 0], e1 = edges[t + 1];
    const uint2 e2 = edges[t + 2], e3 = edges[t + 3];
    const unsigned g0 = hu[(size_t)e0.y * 64 + lane];
    const unsigned g1 = hu[(size_t)e1.y * 64 + lane];
    const unsigned g2 = hu[(size_t)e2.y * 64 + lane];
    const unsigned g3 = hu[(size_t)e3.y * 64 + lane];
    const __half2 h0 = *(const __half2*)&g0;
    const __half2 h1 = *(const __half2*)&g1;
    const __half2 h2 = *(const __half2*)&g2;
    const __half2 h3 = *(const __half2*)&g3;
    const float v0 = __uint_as_float(e0.x), v1 = __uint_as_float(e1.x);
    const float v2 = __uint_as_float(e2.x), v3 = __uint_as_float(e3.x);
    ax = fmaf(v0, __low2float(h0), ax); ay = fmaf(v0, __high2float(h0), ay);
    ax = fmaf(v1, __low2float(h1), ax); ay = fmaf(v1, __high2float(h1), ay);
    ax = fmaf(v2, __low2float(h2), ax); ay = fmaf(v2, __high2float(h2), ay);
    ax = fmaf(v3, __low2float(h3), ax); ay = fmaf(v3, __high2float(h3), ay);
  }
  for (; t < e; ++t) {
    const uint2 ee = edges[t];
    const unsigned g = hu[(size_t)ee.y * 64 + lane];
    const __half2 hh = *(const __half2*)&g;
    const float v = __uint_as_float(ee.x);
    ax = fmaf(v, __low2float(hh), ax); ay = fmaf(v, __high2float(hh), ay);
  }
  float2 o; o.x = ax; o.y = ay;
  ((float2*)agg)[(size_t)node * 64 + lane] = o;
}

// ============ fused single-GEMM fc2 (via W2sq) + softmax ============
// 256 thr, 64x128 tile, thread 8rx4c; A staged once; Ws BK=32 reg-dbuf.
__global__ __launch_bounds__(256) void fc2sm_kernel(const float* __restrict__ agg,
                                                    const float* __restrict__ W2sq,
                                                    const float* __restrict__ b2eff,
                                                    float* __restrict__ out) {
  __shared__ float As[64 * HD];   // 32 KB
  __shared__ float Ws[32 * HD];   // 16 KB
  const int tid = threadIdx.x;
  const int row0 = blockIdx.x * 64;
  const int r0 = (tid >> 5) * 8;
  const int c0 = (tid & 31) * 4;

  float acc[8][4];
  const float4 bb = *(const float4*)&b2eff[c0];
#pragma unroll
  for (int r = 0; r < 8; ++r) {
    acc[r][0] = bb.x; acc[r][1] = bb.y; acc[r][2] = bb.z; acc[r][3] = bb.w;
  }

  // stage A tile once (clamped rows)
#pragma unroll
  for (int i = 0; i < 8; ++i) {
    const int f = tid + i * 256, row = f >> 5, cq = f & 31;
    const int rg = min(row0 + row, NN - 1);
    *(float4*)&As[row * HD + cq * 4] = *(const float4*)&agg[(size_t)rg * HD + cq * 4];
  }
  // prologue: W k-tile 0 -> regs
  float4 wreg[4];
#pragma unroll
  for (int i = 0; i < 4; ++i) {
    const int f = tid + i * 256, k = f >> 5, cq = f & 31;
    wreg[i] = *(const float4*)&W2sq[(size_t)k * HD + cq * 4];
  }

#pragma unroll 1
  for (int kt = 0; kt < 4; ++kt) {
    __syncthreads();
#pragma unroll
    for (int i = 0; i < 4; ++i) {
      const int f = tid + i * 256, k = f >> 5, cq = f & 31;
      *(float4*)&Ws[k * HD + cq * 4] = wreg[i];
    }
    __syncthreads();
    if (kt < 3) {
      const int k0n = (kt + 1) * 32;
#pragma unroll
      for (int i = 0; i < 4; ++i) {
        const int f = tid + i * 256, k = f >> 5, cq = f & 31;
        wreg[i] = *(const float4*)&W2sq[(size_t)(k0n + k) * HD + cq * 4];
      }
    }
    const int kbase = kt * 32;
#pragma unroll 2
    for (int kq = 0; kq < 8; ++kq) {
      float4 a[8];
#pragma unroll
      for (int r = 0; r < 8; ++r)
        a[r] = *(const float4*)&As[(r0 + r) * HD + kbase + kq * 4];
#pragma unroll
      for (int kk = 0; kk < 4; ++kk) {
        const float4 wv = *(const float4*)&Ws[(kq * 4 + kk) * HD + c0];
#pragma unroll
        for (int r = 0; r < 8; ++r) {
          const float av = ((const float*)&a[r])[kk];
          acc[r][0] = fmaf(av, wv.x, acc[r][0]);
          acc[r][1] = fmaf(av, wv.y, acc[r][1]);
          acc[r][2] = fmaf(av, wv.z, acc[r][2]);
          acc[r][3] = fmaf(av, wv.w, acc[r][3]);
        }
      }
    }
  }

  // softmax per row across the 32 threads sharing the row
#pragma unroll 1
  for (int r = 0; r < 8; ++r) {
    float m = fmaxf(fmaxf(acc[r][0], acc[r][1]), fmaxf(acc[r][2], acc[r][3]));
#pragma unroll
    for (int off = 1; off < 32; off <<= 1) m = fmaxf(m, __shfl_xor(m, off));
    float p0 = __expf(acc[r][0] - m);
    float p1 = __expf(acc[r][1] - m);
    float p2 = __expf(acc[r][2] - m);
    float p3 = __expf(acc[r][3] - m);
    float ss = (p0 + p1) + (p2 + p3);
#pragma unroll
    for (int off = 1; off < 32; off <<= 1) ss += __shfl_xor(ss, off);
    const float inv = 1.f / ss;
    const int rg = row0 + r0 + r;
    if (rg < NN) {
      float4 o; o.x = p0 * inv; o.y = p1 * inv; o.z = p2 * inv; o.w = p3 * inv;
      *(float4*)&out[(size_t)rg * HD + c0] = o;
    }
  }
}

// ============ launch ============
extern "C" void kernel_launch(void* const* d_in, const int* in_sizes, int n_in,
                              void* d_out, int out_size, void* d_ws, size_t ws_size,
                              hipStream_t stream) {
  (void)in_sizes; (void)n_in; (void)out_size; (void)ws_size;
  const float* x   = (const float*)d_in[0];
  const float* W1  = (const float*)d_in[1];
  const float* b1  = (const float*)d_in[2];
  const float* W2  = (const float*)d_in[3];
  const float* b2  = (const float*)d_in[4];
  const float* adj_vals = (const float*)d_in[5];
  const int* adj_rows   = (const int*)d_in[6];
  const int* adj_cols   = (const int*)d_in[7];
  float* out = (float*)d_out;

  char* ws = (char*)d_ws;
  __half* h     = (__half*)ws;                           // 12.8 MB
  float* agg    = (float*)(ws + 12800000);               // 25.6 MB
  float* W2sq   = (float*)(ws + 38400000);               // 64 KB
  float* b2eff  = (float*)(ws + 38465536);               // 512 B
  int* row_ptr  = (int*)(ws + 38466048);                 // 50016 ints
  int* cursor   = (int*)(ws + 38666112);
  int* counts   = (int*)(ws + 38866176);
  uint2* edges_s = (uint2*)(ws + 39066240);              // 6.4 MB

  hipMemsetAsync(counts, 0, NN * sizeof(int), stream);

  w2sq_kernel<<<HD, HD, 0, stream>>>(W2, b2, W2sq, b2eff);
  fc1_kernel<<<(NN + 63) / 64, 256, 0, stream>>>(x, W1, b1, h);
  hist_kernel<<<(EE + 255) / 256, 256, 0, stream>>>(adj_rows, counts);
  scan_kernel<<<1, 1024, 0, stream>>>(counts, row_ptr, cursor);
  permute_kernel<<<(EE + 255) / 256, 256, 0, stream>>>(adj_rows, adj_cols, adj_vals,
                                                       cursor, edges_s);
  spmm_kernel<<<(NN + 3) / 4, 256, 0, stream>>>(h, edges_s, row_ptr, agg);
  fc2sm_kernel<<<(NN + 63) / 64, 256, 0, stream>>>(agg, W2sq, b2eff, out);
}

// Round 5
// 322.059 us; speedup vs baseline: 1.6479x; 1.1837x over previous
//
#include <hip/hip_runtime.h>
#include <hip/hip_fp16.h>

#define NN 50000
#define EE 800000
#define IND 256
#define HD 128

// ============ W2sq = W2@W2, b2eff = b2@W2 + b2 (tiny, once per launch) ============
__global__ __launch_bounds__(128) void w2sq_kernel(const float* __restrict__ W2,
                                                   const float* __restrict__ b2,
                                                   float* __restrict__ W2sq,
                                                   float* __restrict__ b2eff) {
  const int r = blockIdx.x;
  const int c = threadIdx.x;
  float acc = 0.f;
#pragma unroll 8
  for (int k = 0; k < HD; ++k)
    acc = fmaf(W2[r * HD + k], W2[k * HD + c], acc);
  W2sq[r * HD + c] = acc;
  if (r == 0) {
    float be = b2[c];
#pragma unroll 8
    for (int k = 0; k < HD; ++k)
      be = fmaf(b2[k], W2[k * HD + c], be);
    b2eff[c] = be;
  }
}

// ============ fc1: h = relu(x @ W1 + b1), h stored fp16 ============
// 256 thr, 64x128 tile, thread 8r x 4c, BK=32 -> 24KB LDS -> 5-6 blocks/CU.
// Plain staging (NO persistent staging regs — R4's reg-dbuf spilled: 68 VGPR,
// 156MB scratch writes). Occupancy/TLP hides staging latency instead.
__global__ __launch_bounds__(256) void fc1_kernel(const float* __restrict__ x,
                                                  const float* __restrict__ W1,
                                                  const float* __restrict__ b1,
                                                  __half* __restrict__ h) {
  __shared__ float As[64 * 32];   // [row][k] 8 KB
  __shared__ float Ws[32 * HD];   // [k][col] 16 KB
  const int tid = threadIdx.x;
  const int row0 = blockIdx.x * 64;
  const int r0 = (tid >> 5) * 8;
  const int c0 = (tid & 31) * 4;

  float acc[8][4];
  const float4 bb = *(const float4*)&b1[c0];
#pragma unroll
  for (int r = 0; r < 8; ++r) {
    acc[r][0] = bb.x; acc[r][1] = bb.y; acc[r][2] = bb.z; acc[r][3] = bb.w;
  }

#pragma unroll 1
  for (int kt = 0; kt < 8; ++kt) {
    const int k0 = kt * 32;
    // stage A: 64 rows x 32 k = 512 float4, 2/thread
#pragma unroll
    for (int i = 0; i < 2; ++i) {
      const int f = tid + i * 256, row = f >> 3, kq = f & 7;
      const int rg = min(row0 + row, NN - 1);
      *(float4*)&As[f * 4] = *(const float4*)&x[(size_t)rg * IND + k0 + kq * 4];
    }
    // stage W: 32 k x 128 c = 1024 float4, 4/thread
#pragma unroll
    for (int i = 0; i < 4; ++i) {
      const int f = tid + i * 256, k = f >> 5, cq = f & 31;
      *(float4*)&Ws[f * 4] = *(const float4*)&W1[(size_t)(k0 + k) * HD + cq * 4];
    }
    __syncthreads();
#pragma unroll 2
    for (int kq = 0; kq < 8; ++kq) {
      float4 a[8];
#pragma unroll
      for (int r = 0; r < 8; ++r) a[r] = *(const float4*)&As[(r0 + r) * 32 + kq * 4];
#pragma unroll
      for (int kk = 0; kk < 4; ++kk) {
        const float4 wv = *(const float4*)&Ws[(kq * 4 + kk) * HD + c0];
#pragma unroll
        for (int r = 0; r < 8; ++r) {
          const float av = ((const float*)&a[r])[kk];
          acc[r][0] = fmaf(av, wv.x, acc[r][0]);
          acc[r][1] = fmaf(av, wv.y, acc[r][1]);
          acc[r][2] = fmaf(av, wv.z, acc[r][2]);
          acc[r][3] = fmaf(av, wv.w, acc[r][3]);
        }
      }
    }
    __syncthreads();
  }
  // epilogue: relu -> fp16 pack -> 8B store
#pragma unroll
  for (int r = 0; r < 8; ++r) {
    const int rg = row0 + r0 + r;
    if (rg < NN) {
      const float o0 = fmaxf(acc[r][0], 0.f), o1 = fmaxf(acc[r][1], 0.f);
      const float o2 = fmaxf(acc[r][2], 0.f), o3 = fmaxf(acc[r][3], 0.f);
      uint2 p;
      p.x = (uint)__half_as_ushort(__float2half(o0)) |
            ((uint)__half_as_ushort(__float2half(o1)) << 16);
      p.y = (uint)__half_as_ushort(__float2half(o2)) |
            ((uint)__half_as_ushort(__float2half(o3)) << 16);
      *(uint2*)&h[(size_t)rg * HD + c0] = p;
    }
  }
}

// ============ CSR build ============
__global__ void hist_kernel(const int* __restrict__ rows, int* __restrict__ counts) {
  int e = blockIdx.x * 256 + threadIdx.x;
  if (e < EE) atomicAdd(&counts[rows[e]], 1);
}

__device__ inline int wave_incl_scan(int v, int lane) {
#pragma unroll
  for (int off = 1; off < 64; off <<= 1) {
    int n = __shfl_up(v, off);
    if (lane >= off) v += n;
  }
  return v;
}

// --- hierarchical scan: 196-block local scan + 1-block partial scan + apply ---
__global__ __launch_bounds__(256) void scan_a_kernel(const int* __restrict__ counts,
                                                     int* __restrict__ incl,
                                                     int* __restrict__ bsum) {
  __shared__ int wtot[4];
  const int t = threadIdx.x;
  const int i = blockIdx.x * 256 + t;
  const int lane = t & 63, wid = t >> 6;
  const int v = (i < NN) ? counts[i] : 0;
  int sc = wave_incl_scan(v, lane);
  if (lane == 63) wtot[wid] = sc;
  __syncthreads();
  int pre = 0;
#pragma unroll
  for (int w = 0; w < 3; ++w) pre += (wid > w) ? wtot[w] : 0;
  if (i < NN) incl[i] = sc + pre;
  if (t == 255) bsum[blockIdx.x] = pre + sc;
}

__global__ __launch_bounds__(256) void scan_b_kernel(int* __restrict__ bsum,
                                                     int* __restrict__ boffs,
                                                     int nblk) {
  __shared__ int wtot[4];
  const int t = threadIdx.x;
  const int lane = t & 63, wid = t >> 6;
  const int v = (t < nblk) ? bsum[t] : 0;
  int sc = wave_incl_scan(v, lane);
  if (lane == 63) wtot[wid] = sc;
  __syncthreads();
  int pre = 0;
#pragma unroll
  for (int w = 0; w < 3; ++w) pre += (wid > w) ? wtot[w] : 0;
  if (t < nblk) boffs[t] = sc + pre - v;  // exclusive block offset
}

__global__ __launch_bounds__(256) void scan_c_kernel(const int* __restrict__ counts,
                                                     const int* __restrict__ incl,
                                                     const int* __restrict__ boffs,
                                                     int* __restrict__ row_ptr,
                                                     int* __restrict__ cursor) {
  const int i = blockIdx.x * 256 + threadIdx.x;
  if (i == 0) row_ptr[0] = 0;
  if (i < NN) {
    const int e = boffs[blockIdx.x] + incl[i];  // inclusive global prefix
    row_ptr[i + 1] = e;
    cursor[i] = e - counts[i];
  }
}

__global__ void permute_kernel(const int* __restrict__ rows, const int* __restrict__ cols,
                               const float* __restrict__ vals, int* __restrict__ cursor,
                               uint2* __restrict__ edges_s) {
  int e = blockIdx.x * 256 + threadIdx.x;
  if (e < EE) {
    int r = rows[e];
    int pos = atomicAdd(&cursor[r], 1);
    edges_s[pos] = make_uint2(__float_as_uint(vals[e]), (unsigned)cols[e]);
  }
}

// ============ SpMM: one wave per node, fp16 h gather (4B/lane), 4-deep ============
__global__ __launch_bounds__(256) void spmm_kernel(const __half* __restrict__ h,
                                                   const uint2* __restrict__ edges,
                                                   const int* __restrict__ row_ptr,
                                                   float* __restrict__ agg) {
  const int wid = threadIdx.x >> 6;
  const int lane = threadIdx.x & 63;
  const int node = blockIdx.x * 4 + wid;
  if (node >= NN) return;
  const int s = row_ptr[node];
  const int e = row_ptr[node + 1];
  const unsigned* __restrict__ hu = (const unsigned*)h;
  float ax = 0.f, ay = 0.f;
  int t = s;
  for (; t + 3 < e; t += 4) {
    const uint2 e0 = edges[t + 0], e1 = edges[t + 1];
    const uint2 e2 = edges[t + 2], e3 = edges[t + 3];
    const unsigned g0 = hu[(size_t)e0.y * 64 + lane];
    const unsigned g1 = hu[(size_t)e1.y * 64 + lane];
    const unsigned g2 = hu[(size_t)e2.y * 64 + lane];
    const unsigned g3 = hu[(size_t)e3.y * 64 + lane];
    const __half2 h0 = *(const __half2*)&g0;
    const __half2 h1 = *(const __half2*)&g1;
    const __half2 h2 = *(const __half2*)&g2;
    const __half2 h3 = *(const __half2*)&g3;
    const float v0 = __uint_as_float(e0.x), v1 = __uint_as_float(e1.x);
    const float v2 = __uint_as_float(e2.x), v3 = __uint_as_float(e3.x);
    ax = fmaf(v0, __low2float(h0), ax); ay = fmaf(v0, __high2float(h0), ay);
    ax = fmaf(v1, __low2float(h1), ax); ay = fmaf(v1, __high2float(h1), ay);
    ax = fmaf(v2, __low2float(h2), ax); ay = fmaf(v2, __high2float(h2), ay);
    ax = fmaf(v3, __low2float(h3), ax); ay = fmaf(v3, __high2float(h3), ay);
  }
  for (; t < e; ++t) {
    const uint2 ee = edges[t];
    const unsigned g = hu[(size_t)ee.y * 64 + lane];
    const __half2 hh = *(const __half2*)&g;
    const float v = __uint_as_float(ee.x);
    ax = fmaf(v, __low2float(hh), ax); ay = fmaf(v, __high2float(hh), ay);
  }
  float2 o; o.x = ax; o.y = ay;
  ((float2*)agg)[(size_t)node * 64 + lane] = o;
}

// ============ fused single-GEMM fc2 (via W2sq) + softmax ============
// 256 thr, 64x128 tile, thread 8r x 4c; As staged once (32KB); Ws BK=32 (16KB).
__global__ __launch_bounds__(256) void fc2sm_kernel(const float* __restrict__ agg,
                                                    const float* __restrict__ W2sq,
                                                    const float* __restrict__ b2eff,
                                                    float* __restrict__ out) {
  __shared__ float As[64 * HD];   // 32 KB
  __shared__ float Ws[32 * HD];   // 16 KB
  const int tid = threadIdx.x;
  const int row0 = blockIdx.x * 64;
  const int r0 = (tid >> 5) * 8;
  const int c0 = (tid & 31) * 4;

  float acc[8][4];
  const float4 bb = *(const float4*)&b2eff[c0];
#pragma unroll
  for (int r = 0; r < 8; ++r) {
    acc[r][0] = bb.x; acc[r][1] = bb.y; acc[r][2] = bb.z; acc[r][3] = bb.w;
  }

  // stage A tile once (clamped rows)
#pragma unroll
  for (int i = 0; i < 8; ++i) {
    const int f = tid + i * 256, row = f >> 5, cq = f & 31;
    const int rg = min(row0 + row, NN - 1);
    *(float4*)&As[f * 4] = *(const float4*)&agg[(size_t)rg * HD + cq * 4];
  }

#pragma unroll 1
  for (int kt = 0; kt < 4; ++kt) {
    const int k0 = kt * 32;
#pragma unroll
    for (int i = 0; i < 4; ++i) {
      const int f = tid + i * 256, k = f >> 5, cq = f & 31;
      *(float4*)&Ws[f * 4] = *(const float4*)&W2sq[(size_t)(k0 + k) * HD + cq * 4];
    }
    __syncthreads();
#pragma unroll 2
    for (int kq = 0; kq < 8; ++kq) {
      float4 a[8];
#pragma unroll
      for (int r = 0; r < 8; ++r)
        a[r] = *(const float4*)&As[(r0 + r) * HD + k0 + kq * 4];
#pragma unroll
      for (int kk = 0; kk < 4; ++kk) {
        const float4 wv = *(const float4*)&Ws[(kq * 4 + kk) * HD + c0];
#pragma unroll
        for (int r = 0; r < 8; ++r) {
          const float av = ((const float*)&a[r])[kk];
          acc[r][0] = fmaf(av, wv.x, acc[r][0]);
          acc[r][1] = fmaf(av, wv.y, acc[r][1]);
          acc[r][2] = fmaf(av, wv.z, acc[r][2]);
          acc[r][3] = fmaf(av, wv.w, acc[r][3]);
        }
      }
    }
    __syncthreads();
  }

  // softmax per row across the 32 threads sharing the row
#pragma unroll 1
  for (int r = 0; r < 8; ++r) {
    float m = fmaxf(fmaxf(acc[r][0], acc[r][1]), fmaxf(acc[r][2], acc[r][3]));
#pragma unroll
    for (int off = 1; off < 32; off <<= 1) m = fmaxf(m, __shfl_xor(m, off));
    float p0 = __expf(acc[r][0] - m);
    float p1 = __expf(acc[r][1] - m);
    float p2 = __expf(acc[r][2] - m);
    float p3 = __expf(acc[r][3] - m);
    float ss = (p0 + p1) + (p2 + p3);
#pragma unroll
    for (int off = 1; off < 32; off <<= 1) ss += __shfl_xor(ss, off);
    const float inv = 1.f / ss;
    const int rg = row0 + r0 + r;
    if (rg < NN) {
      float4 o; o.x = p0 * inv; o.y = p1 * inv; o.z = p2 * inv; o.w = p3 * inv;
      *(float4*)&out[(size_t)rg * HD + c0] = o;
    }
  }
}

// ============ launch ============
extern "C" void kernel_launch(void* const* d_in, const int* in_sizes, int n_in,
                              void* d_out, int out_size, void* d_ws, size_t ws_size,
                              hipStream_t stream) {
  (void)in_sizes; (void)n_in; (void)out_size; (void)ws_size;
  const float* x   = (const float*)d_in[0];
  const float* W1  = (const float*)d_in[1];
  const float* b1  = (const float*)d_in[2];
  const float* W2  = (const float*)d_in[3];
  const float* b2  = (const float*)d_in[4];
  const float* adj_vals = (const float*)d_in[5];
  const int* adj_rows   = (const int*)d_in[6];
  const int* adj_cols   = (const int*)d_in[7];
  float* out = (float*)d_out;

  char* ws = (char*)d_ws;
  __half* h      = (__half*)ws;                          // 12.8 MB
  float* agg     = (float*)(ws + 12800000);              // 25.6 MB
  float* W2sq    = (float*)(ws + 38400000);              // 64 KB
  float* b2eff   = (float*)(ws + 38465536);              // 512 B
  int* row_ptr   = (int*)(ws + 38466048);                // 50016 ints
  int* cursor    = (int*)(ws + 38666112);
  int* counts    = (int*)(ws + 38866176);
  int* incl      = (int*)(ws + 39066240);                // 50016 ints
  int* bsum      = (int*)(ws + 39266304);                // 256 ints
  int* boffs     = (int*)(ws + 39267328);                // 256 ints
  uint2* edges_s = (uint2*)(ws + 39268352);              // 6.4 MB

  const int nblk = (NN + 255) / 256;  // 196

  hipMemsetAsync(counts, 0, NN * sizeof(int), stream);

  w2sq_kernel<<<HD, HD, 0, stream>>>(W2, b2, W2sq, b2eff);
  fc1_kernel<<<(NN + 63) / 64, 256, 0, stream>>>(x, W1, b1, h);
  hist_kernel<<<(EE + 255) / 256, 256, 0, stream>>>(adj_rows, counts);
  scan_a_kernel<<<nblk, 256, 0, stream>>>(counts, incl, bsum);
  scan_b_kernel<<<1, 256, 0, stream>>>(bsum, boffs, nblk);
  scan_c_kernel<<<nblk, 256, 0, stream>>>(counts, incl, boffs, row_ptr, cursor);
  permute_kernel<<<(EE + 255) / 256, 256, 0, stream>>>(adj_rows, adj_cols, adj_vals,
                                                       cursor, edges_s);
  spmm_kernel<<<(NN + 3) / 4, 256, 0, stream>>>(h, edges_s, row_ptr, agg);
  fc2sm_kernel<<<(NN + 63) / 64, 256, 0, stream>>>(agg, W2sq, b2eff, out);
}

// Round 8
// 267.898 us; speedup vs baseline: 1.9810x; 1.2022x over previous
//
#include <hip/hip_runtime.h>
#include <hip/hip_fp16.h>

#define NN 50000
#define EE 800000
#define IND 256
#define HD 128

typedef _Float16 half2v __attribute__((ext_vector_type(2)));
typedef _Float16 half4v __attribute__((ext_vector_type(4)));
typedef _Float16 half8v __attribute__((ext_vector_type(8)));
typedef float f32x4 __attribute__((ext_vector_type(4)));

// ============ prep: W1T fp16 [col][k] (transposed) ============
__global__ __launch_bounds__(128) void w1t_kernel(const float* __restrict__ W1,
                                                  _Float16* __restrict__ W1T) {
  const int k = blockIdx.x;   // 0..255
  const int c = threadIdx.x;  // 0..127
  W1T[c * IND + k] = (_Float16)W1[k * HD + c];
}

// ============ prep: W2sqT fp16 [col][k] = (W2@W2)^T, b2eff = b2@W2 + b2 ============
__global__ __launch_bounds__(128) void w2sq_kernel(const float* __restrict__ W2,
                                                   const float* __restrict__ b2,
                                                   _Float16* __restrict__ W2sqT,
                                                   float* __restrict__ b2eff) {
  const int r = blockIdx.x;   // 0..127
  const int c = threadIdx.x;  // 0..127
  float acc = 0.f;
#pragma unroll 8
  for (int k = 0; k < HD; ++k)
    acc = fmaf(W2[r * HD + k], W2[k * HD + c], acc);
  W2sqT[c * HD + r] = (_Float16)acc;   // transposed store
  if (r == 0) {
    float be = b2[c];
#pragma unroll 8
    for (int k = 0; k < HD; ++k)
      be = fmaf(b2[k], W2[k * HD + c], be);
    b2eff[c] = be;
  }
}

// ============ fc1 (MFMA): h = relu(x @ W1 + b1), h fp16 ============
// 256 thr = 4 waves; block tile 64 rows x 128 cols; wave w: cols [w*32, w*32+32).
// A: x staged f32->f16 in LDS (padded rows). B: W1T fp16 direct from global (L2-hot).
__global__ __launch_bounds__(256) void fc1_kernel(const float* __restrict__ x,
                                                  const _Float16* __restrict__ W1T,
                                                  const float* __restrict__ b1,
                                                  _Float16* __restrict__ h) {
  __shared__ _Float16 As[64 * 40];   // [row][k0..31] pad 40 -> 5 KB
  const int tid = threadIdx.x;
  const int l = tid & 63;
  const int w = tid >> 6;
  const int row0 = blockIdx.x * 64;
  const int lr = l & 15;       // frag row/col lane index
  const int lk = l >> 4;       // frag k-group

  f32x4 acc[4][2];
#pragma unroll
  for (int mi = 0; mi < 4; ++mi)
#pragma unroll
    for (int ni = 0; ni < 2; ++ni) acc[mi][ni] = (f32x4){0.f, 0.f, 0.f, 0.f};

#pragma unroll 1
  for (int kt = 0; kt < 8; ++kt) {
    const int k0 = kt * 32;
    __syncthreads();
    // stage A: 64 rows x 32 k, f32 -> f16 (512 half4v, 2/thread)
#pragma unroll
    for (int i = 0; i < 2; ++i) {
      const int f = tid + i * 256;          // 0..511
      const int row = f >> 3, kq = f & 7;
      const int rg = min(row0 + row, NN - 1);
      const float4 xv = *(const float4*)&x[(size_t)rg * IND + k0 + kq * 4];
      half4v hv = {(_Float16)xv.x, (_Float16)xv.y, (_Float16)xv.z, (_Float16)xv.w};
      *(half4v*)&As[row * 40 + kq * 4] = hv;
    }
    __syncthreads();
    // B frags from global W1T [col][256]
    const half8v b0 = *(const half8v*)&W1T[(size_t)(w * 32 + lr) * IND + k0 + lk * 8];
    const half8v b1f = *(const half8v*)&W1T[(size_t)(w * 32 + 16 + lr) * IND + k0 + lk * 8];
#pragma unroll
    for (int mi = 0; mi < 4; ++mi) {
      const half8v a = *(const half8v*)&As[(mi * 16 + lr) * 40 + lk * 8];
      acc[mi][0] = __builtin_amdgcn_mfma_f32_16x16x32_f16(a, b0, acc[mi][0], 0, 0, 0);
      acc[mi][1] = __builtin_amdgcn_mfma_f32_16x16x32_f16(a, b1f, acc[mi][1], 0, 0, 0);
    }
  }
  // epilogue: +bias, relu, fp16 store. C/D: col=l&15, row=(l>>4)*4+reg.
  const float bias0 = b1[w * 32 + lr];
  const float bias1 = b1[w * 32 + 16 + lr];
#pragma unroll
  for (int mi = 0; mi < 4; ++mi) {
#pragma unroll
    for (int j = 0; j < 4; ++j) {
      const int rg = row0 + mi * 16 + lk * 4 + j;
      if (rg < NN) {
        h[(size_t)rg * HD + w * 32 + lr] = (_Float16)fmaxf(acc[mi][0][j] + bias0, 0.f);
        h[(size_t)rg * HD + w * 32 + 16 + lr] = (_Float16)fmaxf(acc[mi][1][j] + bias1, 0.f);
      }
    }
  }
}

// ============ CSR build ============
__global__ void hist_kernel(const int* __restrict__ rows, int* __restrict__ counts) {
  int e = blockIdx.x * 256 + threadIdx.x;
  if (e < EE) atomicAdd(&counts[rows[e]], 1);
}

__device__ inline int wave_incl_scan(int v, int lane) {
#pragma unroll
  for (int off = 1; off < 64; off <<= 1) {
    int n = __shfl_up(v, off);
    if (lane >= off) v += n;
  }
  return v;
}

__global__ __launch_bounds__(256) void scan_a_kernel(const int* __restrict__ counts,
                                                     int* __restrict__ incl,
                                                     int* __restrict__ bsum) {
  __shared__ int wtot[4];
  const int t = threadIdx.x;
  const int i = blockIdx.x * 256 + t;
  const int lane = t & 63, wid = t >> 6;
  const int v = (i < NN) ? counts[i] : 0;
  int sc = wave_incl_scan(v, lane);
  if (lane == 63) wtot[wid] = sc;
  __syncthreads();
  int pre = 0;
#pragma unroll
  for (int w = 0; w < 3; ++w) pre += (wid > w) ? wtot[w] : 0;
  if (i < NN) incl[i] = sc + pre;
  if (t == 255) bsum[blockIdx.x] = pre + sc;
}

__global__ __launch_bounds__(256) void scan_b_kernel(int* __restrict__ bsum,
                                                     int* __restrict__ boffs,
                                                     int nblk) {
  __shared__ int wtot[4];
  const int t = threadIdx.x;
  const int lane = t & 63, wid = t >> 6;
  const int v = (t < nblk) ? bsum[t] : 0;
  int sc = wave_incl_scan(v, lane);
  if (lane == 63) wtot[wid] = sc;
  __syncthreads();
  int pre = 0;
#pragma unroll
  for (int w = 0; w < 3; ++w) pre += (wid > w) ? wtot[w] : 0;
  if (t < nblk) boffs[t] = sc + pre - v;
}

__global__ __launch_bounds__(256) void scan_c_kernel(const int* __restrict__ counts,
                                                     const int* __restrict__ incl,
                                                     const int* __restrict__ boffs,
                                                     int* __restrict__ row_ptr,
                                                     int* __restrict__ cursor) {
  const int i = blockIdx.x * 256 + threadIdx.x;
  if (i == 0) row_ptr[0] = 0;
  if (i < NN) {
    const int e = boffs[blockIdx.x] + incl[i];
    row_ptr[i + 1] = e;
    cursor[i] = e - counts[i];
  }
}

__global__ void permute_kernel(const int* __restrict__ rows, const int* __restrict__ cols,
                               const float* __restrict__ vals, int* __restrict__ cursor,
                               uint2* __restrict__ edges_s) {
  int e = blockIdx.x * 256 + threadIdx.x;
  if (e < EE) {
    int r = rows[e];
    int pos = atomicAdd(&cursor[r], 1);
    edges_s[pos] = make_uint2(__float_as_uint(vals[e]), (unsigned)cols[e]);
  }
}

// ============ SpMM: one wave per node, fp16 gather, fp16 agg out ============
__global__ __launch_bounds__(256) void spmm_kernel(const _Float16* __restrict__ h,
                                                   const uint2* __restrict__ edges,
                                                   const int* __restrict__ row_ptr,
                                                   _Float16* __restrict__ agg16) {
  const int wid = threadIdx.x >> 6;
  const int lane = threadIdx.x & 63;
  const int node = blockIdx.x * 4 + wid;
  if (node >= NN) return;
  const int s = row_ptr[node];
  const int e = row_ptr[node + 1];
  const unsigned* __restrict__ hu = (const unsigned*)h;
  float ax = 0.f, ay = 0.f;
  int t = s;
  for (; t + 3 < e; t += 4) {
    const uint2 e0 = edges[t + 0], e1 = edges[t + 1];
    const uint2 e2 = edges[t + 2], e3 = edges[t + 3];
    const unsigned g0 = hu[(size_t)e0.y * 64 + lane];
    const unsigned g1 = hu[(size_t)e1.y * 64 + lane];
    const unsigned g2 = hu[(size_t)e2.y * 64 + lane];
    const unsigned g3 = hu[(size_t)e3.y * 64 + lane];
    const __half2 h0 = *(const __half2*)&g0;
    const __half2 h1 = *(const __half2*)&g1;
    const __half2 h2 = *(const __half2*)&g2;
    const __half2 h3 = *(const __half2*)&g3;
    const float v0 = __uint_as_float(e0.x), v1 = __uint_as_float(e1.x);
    const float v2 = __uint_as_float(e2.x), v3 = __uint_as_float(e3.x);
    ax = fmaf(v0, __low2float(h0), ax); ay = fmaf(v0, __high2float(h0), ay);
    ax = fmaf(v1, __low2float(h1), ax); ay = fmaf(v1, __high2float(h1), ay);
    ax = fmaf(v2, __low2float(h2), ax); ay = fmaf(v2, __high2float(h2), ay);
    ax = fmaf(v3, __low2float(h3), ax); ay = fmaf(v3, __high2float(h3), ay);
  }
  for (; t < e; ++t) {
    const uint2 ee = edges[t];
    const unsigned g = hu[(size_t)ee.y * 64 + lane];
    const __half2 hh = *(const __half2*)&g;
    const float v = __uint_as_float(ee.x);
    ax = fmaf(v, __low2float(hh), ax); ay = fmaf(v, __high2float(hh), ay);
  }
  half2v o = {(_Float16)ax, (_Float16)ay};
  *(half2v*)&agg16[(size_t)node * HD + lane * 2] = o;
}

// ============ fc2+softmax (MFMA): out = softmax(agg @ W2sq + b2eff) ============
// 256 thr = 4 waves; tile 64 rows x 128 cols; A (agg fp16) staged once in LDS;
// B = W2sqT fp16 direct from global (32 KB, L2-hot).
__global__ __launch_bounds__(256) void fc2sm_kernel(const _Float16* __restrict__ agg16,
                                                    const _Float16* __restrict__ W2sqT,
                                                    const float* __restrict__ b2eff,
                                                    float* __restrict__ out) {
  __shared__ _Float16 As[64 * 136];   // [row][k0..127] pad 136 -> 17.4 KB
  __shared__ float redm[64][4];
  __shared__ float reds[64][4];
  const int tid = threadIdx.x;
  const int l = tid & 63;
  const int w = tid >> 6;
  const int row0 = blockIdx.x * 64;
  const int lr = l & 15;
  const int lk = l >> 4;

  // stage A: 64 rows x 128 f16 = 1024 uint4, 4/thread
  // (R6 BUG: had 2/thread with row=f>>3,q=f&7 -> cols 64..127 never staged -> NaN)
#pragma unroll
  for (int i = 0; i < 4; ++i) {
    const int f = tid + i * 256;          // 0..1023
    const int row = f >> 4, q = f & 15;
    const int rg = min(row0 + row, NN - 1);
    *(uint4*)&As[row * 136 + q * 8] = *(const uint4*)&agg16[(size_t)rg * HD + q * 8];
  }
  __syncthreads();

  f32x4 acc[4][2];
#pragma unroll
  for (int mi = 0; mi < 4; ++mi)
#pragma unroll
    for (int ni = 0; ni < 2; ++ni) acc[mi][ni] = (f32x4){0.f, 0.f, 0.f, 0.f};

#pragma unroll 2
  for (int kt = 0; kt < 4; ++kt) {
    const int k0 = kt * 32;
    const half8v b0 = *(const half8v*)&W2sqT[(size_t)(w * 32 + lr) * HD + k0 + lk * 8];
    const half8v b1f = *(const half8v*)&W2sqT[(size_t)(w * 32 + 16 + lr) * HD + k0 + lk * 8];
#pragma unroll
    for (int mi = 0; mi < 4; ++mi) {
      const half8v a = *(const half8v*)&As[(mi * 16 + lr) * 136 + k0 + lk * 8];
      acc[mi][0] = __builtin_amdgcn_mfma_f32_16x16x32_f16(a, b0, acc[mi][0], 0, 0, 0);
      acc[mi][1] = __builtin_amdgcn_mfma_f32_16x16x32_f16(a, b1f, acc[mi][1], 0, 0, 0);
    }
  }

  // ---- bias + per-row softmax (row = mi*16 + lk*4 + j; 16 lanes/row/wave) ----
  const float be0 = b2eff[w * 32 + lr];
  const float be1 = b2eff[w * 32 + 16 + lr];
#pragma unroll
  for (int mi = 0; mi < 4; ++mi)
#pragma unroll
    for (int j = 0; j < 4; ++j) {
      acc[mi][0][j] += be0;
      acc[mi][1][j] += be1;
    }
#pragma unroll
  for (int mi = 0; mi < 4; ++mi)
#pragma unroll
    for (int j = 0; j < 4; ++j) {
      float v = fmaxf(acc[mi][0][j], acc[mi][1][j]);
      v = fmaxf(v, __shfl_xor(v, 1));
      v = fmaxf(v, __shfl_xor(v, 2));
      v = fmaxf(v, __shfl_xor(v, 4));
      v = fmaxf(v, __shfl_xor(v, 8));
      if (lr == 0) redm[mi * 16 + lk * 4 + j][w] = v;
    }
  __syncthreads();
#pragma unroll
  for (int mi = 0; mi < 4; ++mi)
#pragma unroll
    for (int j = 0; j < 4; ++j) {
      const int row = mi * 16 + lk * 4 + j;
      const float m = fmaxf(fmaxf(redm[row][0], redm[row][1]),
                            fmaxf(redm[row][2], redm[row][3]));
      const float e0 = __expf(acc[mi][0][j] - m);
      const float e1 = __expf(acc[mi][1][j] - m);
      acc[mi][0][j] = e0;
      acc[mi][1][j] = e1;
      float s = e0 + e1;
      s += __shfl_xor(s, 1);
      s += __shfl_xor(s, 2);
      s += __shfl_xor(s, 4);
      s += __shfl_xor(s, 8);
      if (lr == 0) reds[row][w] = s;
    }
  __syncthreads();
#pragma unroll
  for (int mi = 0; mi < 4; ++mi)
#pragma unroll
    for (int j = 0; j < 4; ++j) {
      const int row = mi * 16 + lk * 4 + j;
      const int rg = row0 + row;
      if (rg < NN) {
        const float inv = 1.f / (((reds[row][0] + reds[row][1]) +
                                  (reds[row][2] + reds[row][3])));
        out[(size_t)rg * HD + w * 32 + lr] = acc[mi][0][j] * inv;
        out[(size_t)rg * HD + w * 32 + 16 + lr] = acc[mi][1][j] * inv;
      }
    }
}

// ============ launch ============
extern "C" void kernel_launch(void* const* d_in, const int* in_sizes, int n_in,
                              void* d_out, int out_size, void* d_ws, size_t ws_size,
                              hipStream_t stream) {
  (void)in_sizes; (void)n_in; (void)out_size; (void)ws_size;
  const float* x   = (const float*)d_in[0];
  const float* W1  = (const float*)d_in[1];
  const float* b1  = (const float*)d_in[2];
  const float* W2  = (const float*)d_in[3];
  const float* b2  = (const float*)d_in[4];
  const float* adj_vals = (const float*)d_in[5];
  const int* adj_rows   = (const int*)d_in[6];
  const int* adj_cols   = (const int*)d_in[7];
  float* out = (float*)d_out;

  char* ws = (char*)d_ws;
  _Float16* h      = (_Float16*)ws;                       // 12.8 MB
  _Float16* agg16  = (_Float16*)(ws + 12800000);          // 12.8 MB
  _Float16* W1T    = (_Float16*)(ws + 25600000);          // 64 KB
  _Float16* W2sqT  = (_Float16*)(ws + 25665536);          // 32 KB
  float* b2eff     = (float*)(ws + 25698304);             // 512 B
  int* row_ptr     = (int*)(ws + 25698816);               // 50016 ints
  int* cursor      = (int*)(ws + 25898880);
  int* counts      = (int*)(ws + 26098944);
  int* incl        = (int*)(ws + 26299008);
  int* bsum        = (int*)(ws + 26499072);               // 256 ints
  int* boffs       = (int*)(ws + 26500096);               // 256 ints
  uint2* edges_s   = (uint2*)(ws + 26501120);             // 6.4 MB

  const int nblk = (NN + 255) / 256;  // 196

  hipMemsetAsync(counts, 0, NN * sizeof(int), stream);

  w1t_kernel<<<IND, HD, 0, stream>>>(W1, W1T);
  w2sq_kernel<<<HD, HD, 0, stream>>>(W2, b2, W2sqT, b2eff);
  fc1_kernel<<<(NN + 63) / 64, 256, 0, stream>>>(x, W1T, b1, h);
  hist_kernel<<<(EE + 255) / 256, 256, 0, stream>>>(adj_rows, counts);
  scan_a_kernel<<<nblk, 256, 0, stream>>>(counts, incl, bsum);
  scan_b_kernel<<<1, 256, 0, stream>>>(bsum, boffs, nblk);
  scan_c_kernel<<<nblk, 256, 0, stream>>>(counts, incl, boffs, row_ptr, cursor);
  permute_kernel<<<(EE + 255) / 256, 256, 0, stream>>>(adj_rows, adj_cols, adj_vals,
                                                       cursor, edges_s);
  spmm_kernel<<<(NN + 3) / 4, 256, 0, stream>>>(h, edges_s, row_ptr, agg16);
  fc2sm_kernel<<<(NN + 63) / 64, 256, 0, stream>>>(agg16, W2sqT, b2eff, out);
}